// Round 8
// baseline (74.590 us; speedup 1.0000x reference)
//
#include <hip/hip_runtime.h>

#define N_NODES 131072
#define C_IN 32
#define C_OUT 32
#define KTAPS 27
#define BN_EPS 1e-5f
#define NPASS 3

typedef __bf16 bf16x8 __attribute__((ext_vector_type(8)));
typedef float  f32x16 __attribute__((ext_vector_type(16)));

// ws layout:
//   xb   : (N_NODES+1) rows x 32 bf16 (row N_NODES = zeros, gather dummy target)
//   wlay : 27 taps x 2 k-halves x 64 lanes x 8 bf16 (55296 B), 32x32x16 A-frag order
//   sums : 32 sum + 32 sumsq (f32)

static __device__ __forceinline__ unsigned short f2bf(float f) {
    unsigned int u = __float_as_uint(f);
    unsigned int r = (u + 0x7FFFu + ((u >> 16) & 1u)) >> 16;  // RNE
    return (unsigned short)r;
}

// ---- prep: blocks 0..511 transpose x; block 512 builds wlay + zero row + zeroes sums ----
__global__ __launch_bounds__(256) void k_prep(const float* __restrict__ in,
                                              const float* __restrict__ w,
                                              unsigned short* __restrict__ xb,
                                              unsigned short* __restrict__ wlay,
                                              float* __restrict__ sums) {
    if (blockIdx.x < N_NODES / 256) {
        const int n = blockIdx.x * 256 + threadIdx.x;
        unsigned short v[C_IN];
#pragma unroll
        for (int c = 0; c < C_IN; ++c) v[c] = f2bf(in[(size_t)c * N_NODES + n]);
        uint4* dst = reinterpret_cast<uint4*>(xb + (size_t)n * C_IN);
#pragma unroll
        for (int q = 0; q < 4; ++q) {
            uint4 pk;
            pk.x = (unsigned)v[q * 8 + 0] | ((unsigned)v[q * 8 + 1] << 16);
            pk.y = (unsigned)v[q * 8 + 2] | ((unsigned)v[q * 8 + 3] << 16);
            pk.z = (unsigned)v[q * 8 + 4] | ((unsigned)v[q * 8 + 5] << 16);
            pk.w = (unsigned)v[q * 8 + 6] | ((unsigned)v[q * 8 + 7] << 16);
            dst[q] = pk;
        }
    } else {
        if (threadIdx.x < 4) {
            uint4 z = {0u, 0u, 0u, 0u};
            reinterpret_cast<uint4*>(xb + (size_t)N_NODES * C_IN)[threadIdx.x] = z;
        }
        if (threadIdx.x < 2 * C_OUT) sums[threadIdx.x] = 0.f;
        // A-frag for mfma_f32_32x32x16_bf16: co = lane&31, k_local = (lane>>5)*8 + j
        // table: wlay[((k*2 + h)*64 + lane)*8 + j] = w[(k*32 + h*16 + k_local)][co]
        for (int g = threadIdx.x; g < KTAPS * 2 * 64; g += 256) {
            const int k = g >> 7;
            const int h = (g >> 6) & 1;
            const int l = g & 63;
            unsigned short wv[8];
#pragma unroll
            for (int j = 0; j < 8; ++j) {
                const int c  = h * 16 + ((l >> 5) << 3) + j;
                const int co = l & 31;
                wv[j] = f2bf(w[(size_t)(k * C_IN + c) * C_OUT + co]);
            }
            uint4 pk;
            pk.x = (unsigned)wv[0] | ((unsigned)wv[1] << 16);
            pk.y = (unsigned)wv[2] | ((unsigned)wv[3] << 16);
            pk.z = (unsigned)wv[4] | ((unsigned)wv[5] << 16);
            pk.w = (unsigned)wv[6] | ((unsigned)wv[7] << 16);
            *reinterpret_cast<uint4*>(wlay + (size_t)g * 8) = pk;
        }
    }
}

// ---- conv: 512 co-resident 512-thread blocks (2/CU), 3 in-phase passes,
//      32 nodes/wave via mfma_f32_32x32x16_bf16, weights in LDS, fused BN stats ----
__global__ __launch_bounds__(512, 4) void k_conv_mfma(const unsigned short* __restrict__ xb,
                                                      const int* __restrict__ neigh,
                                                      const unsigned short* __restrict__ wlay,
                                                      float* __restrict__ out,
                                                      float* __restrict__ sums) {
    __shared__ unsigned short wl[KTAPS * 2 * 64 * 8];  // 55296 B
    __shared__ float bs[C_OUT];
    __shared__ float bq[C_OUT];

    {   // stage weight table (3456 uint4 over 512 threads)
        const uint4* src = reinterpret_cast<const uint4*>(wlay);
        uint4* d = reinterpret_cast<uint4*>(wl);
        for (int i = threadIdx.x; i < KTAPS * 2 * 64; i += 512) d[i] = src[i];
    }
    if (threadIdx.x < C_OUT) { bs[threadIdx.x] = 0.f; bq[threadIdx.x] = 0.f; }
    __syncthreads();

    const int wid  = threadIdx.x >> 6;   // 0..7
    const int lane = threadIdx.x & 63;
    const int col  = lane & 31;          // node within wave tile (B/D col)
    const int kh   = lane >> 5;          // k-subgroup (0: k 0-7, 1: k 8-15)
    const int nb   = blockIdx.x * 256 + wid * 32;

    // neighbor list for this lane's node (lanes 32-63 duplicate 0-31: broadcast lines)
    const int* nrow = neigh + (size_t)(nb + col) * KTAPS;
    int nidx[KTAPS];
#pragma unroll
    for (int k = 0; k < KTAPS; ++k) nidx[k] = nrow[k];

    f32x16 acc = {};

#pragma unroll 1
    for (int p = 0; p < NPASS; ++p) {
        const int lo = (p * N_NODES) / NPASS;
        const int hi = ((p + 1) * N_NODES) / NPASS;
#pragma unroll
        for (int k = 0; k < KTAPS; ++k) {
            const int idx = nidx[k];
            const int src = (idx >= lo) && (idx < hi) ? idx : N_NODES;  // zero row
            const unsigned short* xrow = xb + (size_t)src * C_IN + kh * 8;
            const bf16x8 x0 = *reinterpret_cast<const bf16x8*>(xrow);        // c 0-15 slice
            const bf16x8 x1 = *reinterpret_cast<const bf16x8*>(xrow + 16);   // c 16-31 slice
            const bf16x8 w0 = *reinterpret_cast<const bf16x8*>(wl + ((size_t)(k * 2 + 0) * 64 + lane) * 8);
            const bf16x8 w1 = *reinterpret_cast<const bf16x8*>(wl + ((size_t)(k * 2 + 1) * 64 + lane) * 8);
            acc = __builtin_amdgcn_mfma_f32_32x32x16_bf16(w0, x0, acc, 0, 0, 0);
            acc = __builtin_amdgcn_mfma_f32_32x32x16_bf16(w1, x1, acc, 0, 0, 0);
        }
        __syncthreads();  // keep waves pass-aligned (L2 set = one chunk)
    }

    // D layout: col = lane&31 -> node, row = (reg&3) + 8*(reg>>2) + 4*kh -> c_out
#pragma unroll
    for (int r = 0; r < 16; ++r) {
        const int row = (r & 3) + 8 * (r >> 2) + 4 * kh;
        out[(size_t)row * N_NODES + nb + col] = acc[r];
    }

    // fused BN stats: reduce over 32 node-lanes in-register -> LDS atomics -> global
    float s[16], q[16];
#pragma unroll
    for (int r = 0; r < 16; ++r) { s[r] = acc[r]; q[r] = acc[r] * acc[r]; }
#pragma unroll
    for (int off = 1; off < 32; off <<= 1) {
#pragma unroll
        for (int r = 0; r < 16; ++r) {
            s[r] += __shfl_xor(s[r], off);
            q[r] += __shfl_xor(q[r], off);
        }
    }
    if (col == 0) {  // lanes 0 and 32
#pragma unroll
        for (int r = 0; r < 16; ++r) {
            const int row = (r & 3) + 8 * (r >> 2) + 4 * kh;
            atomicAdd(&bs[row], s[r]);
            atomicAdd(&bq[row], q[r]);
        }
    }
    __syncthreads();
    if (threadIdx.x < C_OUT) {
        atomicAdd(&sums[threadIdx.x], bs[threadIdx.x]);
        atomicAdd(&sums[C_OUT + threadIdx.x], bq[threadIdx.x]);
    }
}

// ---- BN + ReLU in-place ----
__global__ __launch_bounds__(256) void k_bnrelu(float* __restrict__ out,
                                                const float* __restrict__ sums,
                                                const float* __restrict__ gamma,
                                                const float* __restrict__ beta) {
    const size_t gid = (size_t)blockIdx.x * 256 + threadIdx.x;  // over float4s
    const int co = (int)(gid / (N_NODES / 4));
    const float inv_n = 1.0f / (float)N_NODES;
    const float mean = sums[co] * inv_n;
    const float var  = sums[C_OUT + co] * inv_n - mean * mean;
    const float scale = rsqrtf(var + BN_EPS) * gamma[co];
    const float bias  = beta[co] - mean * scale;

    float4* p = reinterpret_cast<float4*>(out);
    float4 v = p[gid];
    v.x = fmaxf(fmaf(v.x, scale, bias), 0.0f);
    v.y = fmaxf(fmaf(v.y, scale, bias), 0.0f);
    v.z = fmaxf(fmaf(v.z, scale, bias), 0.0f);
    v.w = fmaxf(fmaf(v.w, scale, bias), 0.0f);
    p[gid] = v;
}

extern "C" void kernel_launch(void* const* d_in, const int* in_sizes, int n_in,
                              void* d_out, int out_size, void* d_ws, size_t ws_size,
                              hipStream_t stream) {
    const float* data_in = (const float*)d_in[0];
    const int*   neigh   = (const int*)d_in[1];
    const float* weight  = (const float*)d_in[2];
    const float* gamma   = (const float*)d_in[3];
    const float* beta    = (const float*)d_in[4];
    float* out = (float*)d_out;

    unsigned short* xb   = (unsigned short*)d_ws;                        // (N+1)*32 bf16
    unsigned short* wlay = xb + (size_t)(N_NODES + 1) * C_IN;            // 55296 B
    float* sums = (float*)(wlay + (size_t)KTAPS * 2 * 64 * 8);           // 64 f32

    k_prep<<<N_NODES / 256 + 1, 256, 0, stream>>>(data_in, weight, xb, wlay, sums);
    k_conv_mfma<<<N_NODES / 256, 512, 0, stream>>>(xb, neigh, wlay, out, sums);
    k_bnrelu<<<(N_NODES * C_OUT / 4) / 256, 256, 0, stream>>>(out, sums, gamma, beta);
}